// Round 3
// baseline (436.164 us; speedup 1.0000x reference)
//
#include <hip/hip_runtime.h>
#include <stdint.h>

typedef unsigned short bf16u;
typedef float f32x4 __attribute__((ext_vector_type(4)));
typedef short bf16x8 __attribute__((ext_vector_type(8)));
typedef float f4 __attribute__((ext_vector_type(4)));

#define AS1 __attribute__((address_space(1)))
#define AS3 __attribute__((address_space(3)))

__device__ __forceinline__ float b2f(bf16u u) {
  union { uint32_t i; float f; } v; v.i = ((uint32_t)u) << 16; return v.f;
}
__device__ __forceinline__ uint32_t f2b(float f) {
  union { float f; uint32_t i; } v; v.f = f;
  uint32_t i = v.i;
  return (i + 0x7FFFu + ((i >> 16) & 1u)) >> 16; // RNE
}
__device__ __forceinline__ float sigm(float x) { return 1.f / (1.f + __expf(-x)); }
__device__ __forceinline__ float ftanh(float x) {
  float e = __expf(2.f * x);
  return 1.f - 2.f / (e + 1.f);
}

// ---------------- multi-segment fp32->bf16 / fp32 copy ----------------
struct CvtSeg { const float* src; char* dst; int blk0; int count; int tobf16; };
struct CvtArgs { CvtSeg s[12]; int nseg; };

__global__ __launch_bounds__(256)
void cvt_multi(CvtArgs a) {
  int b = blockIdx.x, seg = 0;
  while (seg + 1 < a.nseg && b >= a.s[seg + 1].blk0) ++seg;
  const CvtSeg& S = a.s[seg];
  size_t idx = ((size_t)(b - S.blk0) * 2048) + (size_t)threadIdx.x * 8;
  if ((long long)idx >= S.count) return;
  f4 x = *(const f4*)&S.src[idx];
  f4 y = *(const f4*)&S.src[idx + 4];
  if (S.tobf16) {
    uint4 o;
    o.x = (f2b(x[0]) & 0xffffu) | (f2b(x[1]) << 16);
    o.y = (f2b(x[2]) & 0xffffu) | (f2b(x[3]) << 16);
    o.z = (f2b(y[0]) & 0xffffu) | (f2b(y[1]) << 16);
    o.w = (f2b(y[2]) & 0xffffu) | (f2b(y[3]) << 16);
    *(uint4*)((bf16u*)S.dst + idx) = o;
  } else {
    *(f4*)((float*)S.dst + idx) = x;
    *(f4*)((float*)S.dst + idx + 4) = y;
  }
}

// ------------------------------ GEMM ------------------------------
// C[M,N] = act(A[M,K] @ W[N,K]^T + bias[N]).  Tile: (IT*32) x 128, 4 waves,
// wave tile (IT*16) x 64.  LDS XOR-swizzled per-row: slot c of row r holds
// global k-chunk c^(r&7); fragment reads use slot g^(m&7) -> conflict-free.
struct GemmPtrs {
  const bf16u* A[2];
  const bf16u* W[2];
  const float* bias[2];
  void* C[2];
};

template <int IT, int ACT, int OUTF32>
__global__ __launch_bounds__(256)
void gemm_bt(GemmPtrs p, int N, int K) {
  constexpr int BM = IT * 32;
  __shared__ bf16u sA[BM * 64];
  __shared__ bf16u sB[128 * 64];
  const int z = blockIdx.z;
  const bf16u* __restrict__ A = p.A[z];
  const bf16u* __restrict__ W = p.W[z];
  const float* __restrict__ bias = p.bias[z];

  const int tid  = threadIdx.x;
  const int wave = tid >> 6;
  const int lane = tid & 63;
  const int bn = blockIdx.x, bm = blockIdx.y;

  const int srA = wave * (IT * 8) + (lane >> 3);
  const int srB = wave * 32 + (lane >> 3);
  const int kc  = (lane & 7) ^ ((lane >> 3) & 7);
  const bf16u* ag = A + (size_t)(bm * BM + srA) * K + kc * 8;
  const bf16u* wg = W + (size_t)(bn * 128 + srB) * K + kc * 8;

  const int wm = wave >> 1, wn = wave & 1;
  const int q = lane >> 4, cl = lane & 15;

  int aoff[IT][2], boff[4][2];
#pragma unroll
  for (int i = 0; i < IT; ++i) {
    int m = wm * (IT * 16) + i * 16 + cl;
#pragma unroll
    for (int kk = 0; kk < 2; ++kk)
      aoff[i][kk] = m * 64 + (((q + kk * 4) ^ (m & 7)) * 8);
  }
#pragma unroll
  for (int j = 0; j < 4; ++j) {
    int n = wn * 64 + j * 16 + cl;
#pragma unroll
    for (int kk = 0; kk < 2; ++kk)
      boff[j][kk] = n * 64 + (((q + kk * 4) ^ (n & 7)) * 8);
  }

  f32x4 acc[IT][4] = {};

  for (int k0 = 0; k0 < K; k0 += 64) {
#pragma unroll
    for (int t = 0; t < IT; ++t)
      __builtin_amdgcn_global_load_lds(
          (const AS1 void*)(ag + k0 + (size_t)t * 8 * K),
          (AS3 void*)&sA[wave * IT * 512 + t * 512],
          16, 0, 0);
#pragma unroll
    for (int t = 0; t < 4; ++t)
      __builtin_amdgcn_global_load_lds(
          (const AS1 void*)(wg + k0 + (size_t)t * 8 * K),
          (AS3 void*)&sB[wave * 2048 + t * 512],
          16, 0, 0);
    __syncthreads();
#pragma unroll
    for (int kk = 0; kk < 2; ++kk) {
      bf16x8 af[IT], bfr[4];
#pragma unroll
      for (int i = 0; i < IT; ++i) af[i] = *(const bf16x8*)&sA[aoff[i][kk]];
#pragma unroll
      for (int j = 0; j < 4; ++j) bfr[j] = *(const bf16x8*)&sB[boff[j][kk]];
#pragma unroll
      for (int i = 0; i < IT; ++i)
#pragma unroll
        for (int j = 0; j < 4; ++j)
          acc[i][j] = __builtin_amdgcn_mfma_f32_16x16x32_bf16(af[i], bfr[j], acc[i][j], 0, 0, 0);
    }
    __syncthreads();
  }

  float bv[4];
#pragma unroll
  for (int j = 0; j < 4; ++j)
    bv[j] = bias[bn * 128 + wn * 64 + j * 16 + cl];

  const int row0 = bm * BM + wm * (IT * 16) + q * 4;
  const int col0 = bn * 128 + wn * 64 + cl;
#pragma unroll
  for (int i = 0; i < IT; ++i)
#pragma unroll
    for (int j = 0; j < 4; ++j)
#pragma unroll
      for (int r = 0; r < 4; ++r) {
        float v = acc[i][j][r] + bv[j];
        if (ACT == 1) v = fmaxf(v, 0.f);
        size_t off = (size_t)(row0 + i * 16 + r) * N + (col0 + j * 16);
        if (OUTF32) ((float*)p.C[z])[off] = v;
        else        ((bf16u*)p.C[z])[off] = (bf16u)f2b(v);
      }
}

// ---- gates GEMM: 256x128 tile, 8 waves, BK=32, 4 LDS bufs, fine phases ----
// Same schedule/ledger as the verified 256x256 fine-phase kernel, re-tiled so
// grid = 24x16x2 = 768 blocks = exactly 3 full rounds of 256 CUs (no wave-
// quantization tail; the 256x256 version wasted ~25% in a half-empty round).
// Per K-tile t (32-wide): phase1 {ds_read A-frags + B j0,j1 | STG_A(t+3) |
// barrier | 8 MFMA | barrier}, phase2 {ds_read B j2,j3 | STG_B(t+3) | counted
// vmcnt | barrier | 8 MFMA | barrier}.  Buffer (t+3)&3 was last read at tile
// t-1 -> WAR-safe.  3 loads/thread/tile; steady state 9 in flight; vmcnt(6)
// drains tile t+1 (issued 2 tiles = 4 phases earlier).  Tail: 6/3/0.
// LDS layout per buffer: 2-row groups of 128B; 16B slot s of rgrp g holds
// (row = 2g + (s'>>2), chunk = s'&3), s' = s ^ (g&7).  Linear dest for
// global_load_lds (source-side swizzle), conflict-free ds_read_b128.
__global__ __launch_bounds__(512, 1)
void gemm_gatesf(GemmPtrs p, int N, int K) {
  __shared__ bf16u sA[4][256 * 32];   // 4 x 16 KB
  __shared__ bf16u sB[4][128 * 32];   // 4 x 8 KB   (96 KB total)
  const int z = blockIdx.z;
  const bf16u* __restrict__ A = p.A[z];
  const bf16u* __restrict__ W = p.W[z];
  const float* __restrict__ bias = p.bias[z];

  const int tid  = threadIdx.x;
  const int wave = tid >> 6;          // 0..7
  const int lane = tid & 63;
  const int bn = blockIdx.x, bm = blockIdx.y;

  // staging decode: rgrp = wave*8 + (lane>>3) (+64 for 2nd A round), slot=lane&7
  // s' = slot ^ (rgrp&7); row = 2*rgrp + (s'>>2); chunk = s'&3.
  // (rgrp&7) invariant under +64 -> same sp for both A rounds.
  const int rg0 = wave * 8 + (lane >> 3);   // 0..63
  const int sp  = (lane & 7) ^ (rg0 & 7);
  const int srow = rg0 * 2 + (sp >> 2);     // 0..127
  const int sch  = sp & 3;
  const bf16u* agA = A + (size_t)(bm * 256 + srow) * K + sch * 8;
  const bf16u* wgB = W + (size_t)(bn * 128 + srow) * K + sch * 8;
  const int ldsoff = wave * 512;            // (wave*8 rgrps) * 64 elems

  const int wm = wave >> 1, wn = wave & 1;  // 4M x 2N waves, wave tile 64x64
  const int q = lane >> 4, cl = lane & 15;

  int aoff[4], boff[4];
#pragma unroll
  for (int m = 0; m < 4; ++m) {
    int row = wm * 64 + m * 16 + cl;
    aoff[m] = (row >> 1) * 64 + (((((row & 1) << 2) | q) ^ ((row >> 1) & 7)) * 8);
  }
#pragma unroll
  for (int j = 0; j < 4; ++j) {
    int row = wn * 64 + j * 16 + cl;
    boff[j] = (row >> 1) * 64 + (((((row & 1) << 2) | q) ^ ((row >> 1) & 7)) * 8);
  }

  f32x4 acc[4][4] = {};
  const int NT = K >> 5;   // 32-wide K-tiles (gates: 32; requires NT >= 4)

#define STG_A(buf, t)                                                         \
  do {                                                                        \
    __builtin_amdgcn_global_load_lds((const AS1 void*)(agA + (t) * 32),       \
        (AS3 void*)&sA[buf][ldsoff], 16, 0, 0);                               \
    __builtin_amdgcn_global_load_lds((const AS1 void*)(agA + (t) * 32 + (size_t)128 * K), \
        (AS3 void*)&sA[buf][ldsoff + 4096], 16, 0, 0);                        \
  } while (0)
#define STG_B(buf, t)                                                         \
  do {                                                                        \
    __builtin_amdgcn_global_load_lds((const AS1 void*)(wgB + (t) * 32),       \
        (AS3 void*)&sB[buf][ldsoff], 16, 0, 0);                               \
  } while (0)

  // prologue: stage tiles 0,1,2 (9 loads/thread in flight)
  STG_A(0, 0); STG_B(0, 0);
  STG_A(1, 1); STG_B(1, 1);
  STG_A(2, 2); STG_B(2, 2);
  asm volatile("s_waitcnt vmcnt(6)" ::: "memory");   // tile 0 landed
  __builtin_amdgcn_s_barrier();
  asm volatile("" ::: "memory");

  for (int t = 0; t < NT; ++t) {
    const int cb = t & 3;
    const int pb = (t + 3) & 3;
    const bool st = (t + 3) < NT;
    bf16x8 af[4], b0, b1;
    // ---------------- phase 1: A frags + B j0,j1 ----------------
#pragma unroll
    for (int m = 0; m < 4; ++m) af[m] = *(const bf16x8*)&sA[cb][aoff[m]];
    b0 = *(const bf16x8*)&sB[cb][boff[0]];
    b1 = *(const bf16x8*)&sB[cb][boff[1]];
    if (st) STG_A(pb, t + 3);
    __builtin_amdgcn_s_barrier();
    asm volatile("" ::: "memory");
    __builtin_amdgcn_s_setprio(1);
#pragma unroll
    for (int m = 0; m < 4; ++m) {
      acc[m][0] = __builtin_amdgcn_mfma_f32_16x16x32_bf16(af[m], b0, acc[m][0], 0, 0, 0);
      acc[m][1] = __builtin_amdgcn_mfma_f32_16x16x32_bf16(af[m], b1, acc[m][1], 0, 0, 0);
    }
    __builtin_amdgcn_s_setprio(0);
    __builtin_amdgcn_s_barrier();
    asm volatile("" ::: "memory");
    // ---------------- phase 2: B j2,j3 ----------------
    b0 = *(const bf16x8*)&sB[cb][boff[2]];
    b1 = *(const bf16x8*)&sB[cb][boff[3]];
    if (st) STG_B(pb, t + 3);
    {
      int nif = NT - 1 - t; if (nif > 3) nif = 3;
      if (nif >= 3)      asm volatile("s_waitcnt vmcnt(6)" ::: "memory");
      else if (nif == 2) asm volatile("s_waitcnt vmcnt(3)" ::: "memory");
      else if (nif == 1) asm volatile("s_waitcnt vmcnt(0)" ::: "memory");
    }
    __builtin_amdgcn_s_barrier();
    asm volatile("" ::: "memory");
    __builtin_amdgcn_s_setprio(1);
#pragma unroll
    for (int m = 0; m < 4; ++m) {
      acc[m][2] = __builtin_amdgcn_mfma_f32_16x16x32_bf16(af[m], b0, acc[m][2], 0, 0, 0);
      acc[m][3] = __builtin_amdgcn_mfma_f32_16x16x32_bf16(af[m], b1, acc[m][3], 0, 0, 0);
    }
    __builtin_amdgcn_s_setprio(0);
    __builtin_amdgcn_s_barrier();
    asm volatile("" ::: "memory");
  }
#undef STG_A
#undef STG_B

  float bv[4];
#pragma unroll
  for (int j = 0; j < 4; ++j)
    bv[j] = bias[bn * 128 + wn * 64 + j * 16 + cl];

  const int row0 = bm * 256 + wm * 64 + q * 4;
  const int col0 = bn * 128 + wn * 64 + cl;
#pragma unroll
  for (int m = 0; m < 4; ++m)
#pragma unroll
    for (int j = 0; j < 4; ++j)
#pragma unroll
      for (int r = 0; r < 4; ++r) {
        float v = acc[m][j][r] + bv[j];
        size_t off = (size_t)(row0 + m * 16 + r) * N + (col0 + j * 16);
        ((bf16u*)p.C[z])[off] = (bf16u)f2b(v);
      }
}

// Heads GEMM: A[M,1024] @ Wp[2304,1024]^T + biasp[2304], packed [mu|sg|pi].
// Tile (IT*32)x128 (gemm_bt structure); head = bn/6 uniform per block.
// mu -> out, softplus(sg) -> out+HS, pi raw fp32 -> rawpi. Head col stride 768.
template <int IT>
__global__ __launch_bounds__(256)
void gemm_heads(const bf16u* __restrict__ A, const bf16u* __restrict__ Wp,
                const float* __restrict__ biasp, float* __restrict__ out_mu,
                float* __restrict__ out_sg, float* __restrict__ rawpi,
                int outHS) {
  constexpr int K = 1024;
  constexpr int BM = IT * 32;
  __shared__ bf16u sA[BM * 64];
  __shared__ bf16u sB[128 * 64];
  const int tid  = threadIdx.x;
  const int wave = tid >> 6;
  const int lane = tid & 63;
  const int bn = blockIdx.x, bm = blockIdx.y;

  const int srA = wave * (IT * 8) + (lane >> 3);
  const int srB = wave * 32 + (lane >> 3);
  const int kc  = (lane & 7) ^ ((lane >> 3) & 7);
  const bf16u* ag = A + (size_t)(bm * BM + srA) * K + kc * 8;
  const bf16u* wg = Wp + (size_t)(bn * 128 + srB) * K + kc * 8;

  const int wm = wave >> 1, wn = wave & 1;
  const int q = lane >> 4, cl = lane & 15;

  int aoff[IT][2], boff[4][2];
#pragma unroll
  for (int i = 0; i < IT; ++i) {
    int m = wm * (IT * 16) + i * 16 + cl;
#pragma unroll
    for (int kk = 0; kk < 2; ++kk)
      aoff[i][kk] = m * 64 + (((q + kk * 4) ^ (m & 7)) * 8);
  }
#pragma unroll
  for (int j = 0; j < 4; ++j) {
    int n = wn * 64 + j * 16 + cl;
#pragma unroll
    for (int kk = 0; kk < 2; ++kk)
      boff[j][kk] = n * 64 + (((q + kk * 4) ^ (n & 7)) * 8);
  }

  f32x4 acc[IT][4] = {};
  for (int k0 = 0; k0 < K; k0 += 64) {
#pragma unroll
    for (int t = 0; t < IT; ++t)
      __builtin_amdgcn_global_load_lds(
          (const AS1 void*)(ag + k0 + (size_t)t * 8 * K),
          (AS3 void*)&sA[wave * IT * 512 + t * 512],
          16, 0, 0);
#pragma unroll
    for (int t = 0; t < 4; ++t)
      __builtin_amdgcn_global_load_lds(
          (const AS1 void*)(wg + k0 + (size_t)t * 8 * K),
          (AS3 void*)&sB[wave * 2048 + t * 512],
          16, 0, 0);
    __syncthreads();
#pragma unroll
    for (int kk = 0; kk < 2; ++kk) {
      bf16x8 af[IT], bfr[4];
#pragma unroll
      for (int i = 0; i < IT; ++i) af[i] = *(const bf16x8*)&sA[aoff[i][kk]];
#pragma unroll
      for (int j = 0; j < 4; ++j) bfr[j] = *(const bf16x8*)&sB[boff[j][kk]];
#pragma unroll
      for (int i = 0; i < IT; ++i)
#pragma unroll
        for (int j = 0; j < 4; ++j)
          acc[i][j] = __builtin_amdgcn_mfma_f32_16x16x32_bf16(af[i], bfr[j], acc[i][j], 0, 0, 0);
    }
    __syncthreads();
  }

  float bv[4];
#pragma unroll
  for (int j = 0; j < 4; ++j)
    bv[j] = biasp[bn * 128 + wn * 64 + j * 16 + cl];

  const int head = bn / 6;                       // 0:mu 1:sg 2:pi
  const int ch0 = (bn % 6) * 128 + wn * 64 + cl; // col within head
  const int row0 = bm * BM + wm * (IT * 16) + q * 4;
#pragma unroll
  for (int i = 0; i < IT; ++i)
#pragma unroll
    for (int j = 0; j < 4; ++j)
#pragma unroll
      for (int r = 0; r < 4; ++r) {
        float v = acc[i][j][r] + bv[j];
        size_t off = (size_t)(row0 + i * 16 + r) * 768 + (ch0 + j * 16);
        if (head == 0) out_mu[off] = v;
        else if (head == 1)
          out_sg[(size_t)0 + off] = fmaxf(v, 0.f) + log1pf(__expf(-fabsf(v)));
        else rawpi[off] = v;
      }
}

struct __align__(16) V8 { uint32_t u[4]; };
__device__ __forceinline__ float getf(const V8& v, int k) {
  uint32_t w = v.u[k >> 1];
  return b2f((bf16u)((k & 1) ? (w >> 16) : (w & 0xffffu)));
}
__device__ __forceinline__ void setb(V8& v, int k, float f) {
  uint32_t b = f2b(f) & 0xffffu;
  if (k & 1) v.u[k >> 1] = (v.u[k >> 1] & 0x0000ffffu) | (b << 16);
  else       v.u[k >> 1] = (v.u[k >> 1] & 0xffff0000u) | b;
}

// PyTorch GRU cell gate math (r,z,n order). 8 elems/thread.
template <int LAST>
__global__ __launch_bounds__(256)
void gru_gates(const bf16u* __restrict__ gi, const bf16u* __restrict__ gh,
               const float* __restrict__ hprev, float* __restrict__ hid_out,
               bf16u* __restrict__ nxt) {
  int t = blockIdx.x * 256 + threadIdx.x;
  size_t idx = (size_t)t * 8;
  int b = (int)(idx >> 10);
  int h = (int)(idx & 1023);
  size_t g0 = (size_t)b * 3072 + h;
  V8 ir  = *(const V8*)&gi[g0];
  V8 izv = *(const V8*)&gi[g0 + 1024];
  V8 inv = *(const V8*)&gi[g0 + 2048];
  V8 hr  = *(const V8*)&gh[g0];
  V8 hzv = *(const V8*)&gh[g0 + 1024];
  V8 hnv = *(const V8*)&gh[g0 + 2048];
  f4 hp0 = *(const f4*)&hprev[idx];
  f4 hp1 = *(const f4*)&hprev[idx + 4];
  f4 o0, o1;
  V8 no = {};
#pragma unroll
  for (int k = 0; k < 8; ++k) {
    float hpv = (k < 4) ? hp0[k] : hp1[k - 4];
    float r  = sigm(getf(ir, k) + getf(hr, k));
    float zg = sigm(getf(izv, k) + getf(hzv, k));
    float n  = ftanh(getf(inv, k) + r * getf(hnv, k));
    float hnew = (1.f - zg) * n + zg * hpv;
    if (k < 4) o0[k] = hnew; else o1[k - 4] = hnew;
    setb(no, k, LAST ? ftanh(hnew) : hnew);
  }
  *(f4*)&hid_out[idx] = o0;
  *(f4*)&hid_out[idx + 4] = o1;
  *(V8*)&nxt[idx] = no;
}

// softmax over g in {o, o+256, o+512} of rawpi [Bc][768] fp32 -> out fp32.
__global__ __launch_bounds__(256)
void pi_softmax(const float* __restrict__ rawpi, float* __restrict__ out) {
  int t = blockIdx.x * 256 + threadIdx.x;  // Bc*64 threads, 4 o's each
  int b = t >> 6;
  int o4 = (t & 63) << 2;
  size_t rb = (size_t)b * 768 + o4;
  f4 pi0 = *(const f4*)&rawpi[rb];
  f4 pi1 = *(const f4*)&rawpi[rb + 256];
  f4 pi2 = *(const f4*)&rawpi[rb + 512];
  f4 e0v, e1v, e2v;
#pragma unroll
  for (int c = 0; c < 4; ++c) {
    float m = fmaxf(fmaxf(pi0[c], pi1[c]), pi2[c]);
    float e0 = __expf(pi0[c] - m), e1 = __expf(pi1[c] - m), e2 = __expf(pi2[c] - m);
    float s = 1.f / (e0 + e1 + e2);
    e0v[c] = e0 * s; e1v[c] = e1 * s; e2v[c] = e2 * s;
  }
  *(f4*)&out[rb]       = e0v;
  *(f4*)&out[rb + 256] = e1v;
  *(f4*)&out[rb + 512] = e2v;
}

extern "C" void kernel_launch(void* const* d_in, const int* in_sizes, int n_in,
                              void* d_out, int out_size, void* d_ws, size_t ws_size,
                              hipStream_t stream) {
  const float* x      = (const float*)d_in[0];
  const float* hidden = (const float*)d_in[1];   // [2][4096][1024]
  const float* i2d_w  = (const float*)d_in[2];
  const float* i2d_b  = (const float*)d_in[3];
  const float* w_ih   = (const float*)d_in[4];   // [2][3072][1024]
  const float* w_hh   = (const float*)d_in[5];
  const float* b_ih   = (const float*)d_in[6];
  const float* b_hh   = (const float*)d_in[7];
  const float* mu_w   = (const float*)d_in[8];
  const float* mu_b   = (const float*)d_in[9];
  const float* sg_w   = (const float*)d_in[10];
  const float* sg_b   = (const float*)d_in[11];
  const float* pi_w   = (const float*)d_in[12];
  const float* pi_b   = (const float*)d_in[13];
  float* out = (float*)d_out;

  const size_t BH = 4194304;      // 4096*1024
  const int HS = 3145728;         // 4096*768
  float* hid_base = out + (size_t)3 * HS;

  dim3 blk(256, 1, 1);

  // ---- ws: bf16 weights (29.5 MB) + packed head bias fp32 ----
  bf16u* wb_i2d = (bf16u*)d_ws;             // 524288
  bf16u* wb_ih  = wb_i2d + 524288;          // 6291456 (both layers)
  bf16u* wb_hh  = wb_ih + 6291456;          // 6291456
  bf16u* wb_hd  = wb_hh + 6291456;          // 2359296 packed [mu|sg|pi][768][1024]
  float* biasp  = (float*)((char*)d_ws + 30932992);  // 2304 fp32
  const size_t wbytes = 30942208;

  { // one dispatch: 6 weight cvts + 3 bias copies
    CvtArgs a{};
    int nb = 0;
    auto seg = [&](const float* s, void* d, int count, int tobf) {
      a.s[a.nseg++] = {s, (char*)d, nb, count, tobf};
      nb += (count + 2047) / 2048;
    };
    seg(i2d_w, wb_i2d, 524288, 1);
    seg(w_ih,  wb_ih, 6291456, 1);
    seg(w_hh,  wb_hh, 6291456, 1);
    seg(mu_w,  wb_hd, 786432, 1);
    seg(sg_w,  wb_hd + 786432, 786432, 1);
    seg(pi_w,  wb_hd + 1572864, 786432, 1);
    seg(mu_b,  biasp, 768, 0);
    seg(sg_b,  biasp + 768, 768, 0);
    seg(pi_b,  biasp + 1536, 768, 0);
    cvt_multi<<<dim3(nb), blk, 0, stream>>>(a);
  }

  // ---- per-chunk scratch: Bc*19456 B ----
  int Bc = 4096;
  while (wbytes + (size_t)Bc * 19456 > ws_size && Bc > 256) Bc >>= 1;
  const int nchunk = 4096 / Bc;

  char* cbase = (char*)d_ws + wbytes;
  bf16u* ws0 = (bf16u*)cbase;                          // h1/hnew/hout bf16
  bf16u* xb  = (bf16u*)(cbase + (size_t)Bc * 2048);
  bf16u* hb0 = (bf16u*)(cbase + (size_t)Bc * 3072);
  bf16u* hb1 = (bf16u*)(cbase + (size_t)Bc * 5120);
  bf16u* gi  = (bf16u*)(cbase + (size_t)Bc * 7168);
  bf16u* gh  = (bf16u*)(cbase + (size_t)Bc * 13312);
  float* rawpi = (float*)gi;  // Bc*3072B, overlays dead gi

  for (int c = 0; c < nchunk; ++c) {
    const size_t off = (size_t)c * Bc;
    const float* h0_c = hidden + off * 1024;
    const float* h1_c = hidden + BH + off * 1024;

    { // one dispatch: x, h0, h1 cvt
      CvtArgs a{};
      int nb = 0;
      auto seg = [&](const float* s, void* d, int count) {
        a.s[a.nseg++] = {s, (char*)d, nb, count, 1};
        nb += (count + 2047) / 2048;
      };
      seg(x + off * 512, xb, Bc * 512);
      seg(h0_c, hb0, Bc * 1024);
      seg(h1_c, hb1, Bc * 1024);
      cvt_multi<<<dim3(nb), blk, 0, stream>>>(a);
    }

    { // h1 = relu(x @ i2d_w^T + b)  M=Bc N=1024 K=512, 64x128 tiles
      GemmPtrs p{};
      p.A[0] = xb; p.W[0] = wb_i2d; p.bias[0] = i2d_b; p.C[0] = ws0;
      gemm_bt<2, 1, 0><<<dim3(8, Bc / 64, 1), blk, 0, stream>>>(p, 1024, 512);
    }
    { // layer 0 gates: 256x128 fine-phase pipeline, 768-block grid
      GemmPtrs p{};
      p.A[0] = ws0; p.W[0] = wb_ih; p.bias[0] = b_ih; p.C[0] = gi;
      p.A[1] = hb0; p.W[1] = wb_hh; p.bias[1] = b_hh; p.C[1] = gh;
      gemm_gatesf<<<dim3(24, Bc / 256, 2), dim3(512, 1, 1), 0, stream>>>(p, 3072, 1024);
    }
    gru_gates<0><<<dim3(Bc / 2), blk, 0, stream>>>(
        gi, gh, h0_c, hid_base + off * 1024, ws0);
    { // layer 1 gates
      GemmPtrs p{};
      p.A[0] = ws0; p.W[0] = wb_ih + 3145728; p.bias[0] = b_ih + 3072; p.C[0] = gi;
      p.A[1] = hb1; p.W[1] = wb_hh + 3145728; p.bias[1] = b_hh + 3072; p.C[1] = gh;
      gemm_gatesf<<<dim3(24, Bc / 256, 2), dim3(512, 1, 1), 0, stream>>>(p, 3072, 1024);
    }
    gru_gates<1><<<dim3(Bc / 2), blk, 0, stream>>>(
        gi, gh, h1_c, hid_base + BH + off * 1024, ws0);
    // heads: 128x128 tiles, packed N=2304; mu/softplus direct, pi to raw
    gemm_heads<4><<<dim3(18, Bc / 128, 1), blk, 0, stream>>>(
        ws0, wb_hd, biasp, out + off * 768, out + HS + off * 768, rawpi, HS);
    pi_softmax<<<dim3(Bc / 4), blk, 0, stream>>>(rawpi, out + 2 * (size_t)HS + off * 768);
  }
}

// Round 4
// 401.500 us; speedup vs baseline: 1.0863x; 1.0863x over previous
//
#include <hip/hip_runtime.h>
#include <stdint.h>

typedef unsigned short bf16u;
typedef float f32x4 __attribute__((ext_vector_type(4)));
typedef short bf16x8 __attribute__((ext_vector_type(8)));
typedef float f4 __attribute__((ext_vector_type(4)));

#define AS1 __attribute__((address_space(1)))
#define AS3 __attribute__((address_space(3)))

__device__ __forceinline__ float b2f(bf16u u) {
  union { uint32_t i; float f; } v; v.i = ((uint32_t)u) << 16; return v.f;
}
__device__ __forceinline__ uint32_t f2b(float f) {
  union { float f; uint32_t i; } v; v.f = f;
  uint32_t i = v.i;
  return (i + 0x7FFFu + ((i >> 16) & 1u)) >> 16; // RNE
}
__device__ __forceinline__ float sigm(float x) { return 1.f / (1.f + __expf(-x)); }
__device__ __forceinline__ float ftanh(float x) {
  float e = __expf(2.f * x);
  return 1.f - 2.f / (e + 1.f);
}

// ---------------- multi-segment fp32->bf16 / fp32 copy ----------------
struct CvtSeg { const float* src; char* dst; int blk0; int count; int tobf16; };
struct CvtArgs { CvtSeg s[12]; int nseg; };

__global__ __launch_bounds__(256)
void cvt_multi(CvtArgs a) {
  int b = blockIdx.x, seg = 0;
  while (seg + 1 < a.nseg && b >= a.s[seg + 1].blk0) ++seg;
  const CvtSeg& S = a.s[seg];
  size_t idx = ((size_t)(b - S.blk0) * 2048) + (size_t)threadIdx.x * 8;
  if ((long long)idx >= S.count) return;
  f4 x = *(const f4*)&S.src[idx];
  f4 y = *(const f4*)&S.src[idx + 4];
  if (S.tobf16) {
    uint4 o;
    o.x = (f2b(x[0]) & 0xffffu) | (f2b(x[1]) << 16);
    o.y = (f2b(x[2]) & 0xffffu) | (f2b(x[3]) << 16);
    o.z = (f2b(y[0]) & 0xffffu) | (f2b(y[1]) << 16);
    o.w = (f2b(y[2]) & 0xffffu) | (f2b(y[3]) << 16);
    *(uint4*)((bf16u*)S.dst + idx) = o;
  } else {
    *(f4*)((float*)S.dst + idx) = x;
    *(f4*)((float*)S.dst + idx + 4) = y;
  }
}

// ------------------------------ GEMM ------------------------------
// C[M,N] = act(A[M,K] @ W[N,K]^T + bias[N]).  Tile: (IT*32) x 128, 4 waves,
// wave tile (IT*16) x 64.  LDS XOR-swizzled per-row: slot c of row r holds
// global k-chunk c^(r&7); fragment reads use slot g^(m&7) -> conflict-free.
struct GemmPtrs {
  const bf16u* A[2];
  const bf16u* W[2];
  const float* bias[2];
  void* C[2];
};

template <int IT, int ACT, int OUTF32>
__global__ __launch_bounds__(256)
void gemm_bt(GemmPtrs p, int N, int K) {
  constexpr int BM = IT * 32;
  __shared__ bf16u sA[BM * 64];
  __shared__ bf16u sB[128 * 64];
  const int z = blockIdx.z;
  const bf16u* __restrict__ A = p.A[z];
  const bf16u* __restrict__ W = p.W[z];
  const float* __restrict__ bias = p.bias[z];

  const int tid  = threadIdx.x;
  const int wave = tid >> 6;
  const int lane = tid & 63;
  const int bn = blockIdx.x, bm = blockIdx.y;

  const int srA = wave * (IT * 8) + (lane >> 3);
  const int srB = wave * 32 + (lane >> 3);
  const int kc  = (lane & 7) ^ ((lane >> 3) & 7);
  const bf16u* ag = A + (size_t)(bm * BM + srA) * K + kc * 8;
  const bf16u* wg = W + (size_t)(bn * 128 + srB) * K + kc * 8;

  const int wm = wave >> 1, wn = wave & 1;
  const int q = lane >> 4, cl = lane & 15;

  int aoff[IT][2], boff[4][2];
#pragma unroll
  for (int i = 0; i < IT; ++i) {
    int m = wm * (IT * 16) + i * 16 + cl;
#pragma unroll
    for (int kk = 0; kk < 2; ++kk)
      aoff[i][kk] = m * 64 + (((q + kk * 4) ^ (m & 7)) * 8);
  }
#pragma unroll
  for (int j = 0; j < 4; ++j) {
    int n = wn * 64 + j * 16 + cl;
#pragma unroll
    for (int kk = 0; kk < 2; ++kk)
      boff[j][kk] = n * 64 + (((q + kk * 4) ^ (n & 7)) * 8);
  }

  f32x4 acc[IT][4] = {};

  for (int k0 = 0; k0 < K; k0 += 64) {
#pragma unroll
    for (int t = 0; t < IT; ++t)
      __builtin_amdgcn_global_load_lds(
          (const AS1 void*)(ag + k0 + (size_t)t * 8 * K),
          (AS3 void*)&sA[wave * IT * 512 + t * 512],
          16, 0, 0);
#pragma unroll
    for (int t = 0; t < 4; ++t)
      __builtin_amdgcn_global_load_lds(
          (const AS1 void*)(wg + k0 + (size_t)t * 8 * K),
          (AS3 void*)&sB[wave * 2048 + t * 512],
          16, 0, 0);
    __syncthreads();
#pragma unroll
    for (int kk = 0; kk < 2; ++kk) {
      bf16x8 af[IT], bfr[4];
#pragma unroll
      for (int i = 0; i < IT; ++i) af[i] = *(const bf16x8*)&sA[aoff[i][kk]];
#pragma unroll
      for (int j = 0; j < 4; ++j) bfr[j] = *(const bf16x8*)&sB[boff[j][kk]];
#pragma unroll
      for (int i = 0; i < IT; ++i)
#pragma unroll
        for (int j = 0; j < 4; ++j)
          acc[i][j] = __builtin_amdgcn_mfma_f32_16x16x32_bf16(af[i], bfr[j], acc[i][j], 0, 0, 0);
    }
    __syncthreads();
  }

  float bv[4];
#pragma unroll
  for (int j = 0; j < 4; ++j)
    bv[j] = bias[bn * 128 + wn * 64 + j * 16 + cl];

  const int row0 = bm * BM + wm * (IT * 16) + q * 4;
  const int col0 = bn * 128 + wn * 64 + cl;
#pragma unroll
  for (int i = 0; i < IT; ++i)
#pragma unroll
    for (int j = 0; j < 4; ++j)
#pragma unroll
      for (int r = 0; r < 4; ++r) {
        float v = acc[i][j][r] + bv[j];
        if (ACT == 1) v = fmaxf(v, 0.f);
        size_t off = (size_t)(row0 + i * 16 + r) * N + (col0 + j * 16);
        if (OUTF32) ((float*)p.C[z])[off] = v;
        else        ((bf16u*)p.C[z])[off] = (bf16u)f2b(v);
      }
}

// ---- gates GEMM: 256x128 tile, 8 waves, BK=32, 4 LDS bufs, fine phases ----
// grid = 24x16x2 = 768 blocks = exactly 3 full rounds of 256 CUs.
// Per K-tile t (32-wide): phase1 {ds_read A-frags + B j0,j1 | STG_A(t+3) |
// barrier | 8 MFMA | barrier}, phase2 {ds_read B j2,j3 | STG_B(t+3) | counted
// vmcnt | barrier | 8 MFMA | barrier}.  Buffer (t+3)&3 was last read at tile
// t-1 -> WAR-safe.  3 loads/thread/tile; steady state 9 in flight; vmcnt(6)
// drains tile t+1 (issued 2 tiles = 4 phases earlier).  Tail: 6/3/0.
// LDS layout per buffer: 2-row groups of 128B; 16B slot s of rgrp g holds
// (row = 2g + (s'>>2), chunk = s'&3), s' = s ^ (g&7).  Linear dest for
// global_load_lds (source-side swizzle), conflict-free ds_read_b128.
__global__ __launch_bounds__(512, 1)
void gemm_gatesf(GemmPtrs p, int N, int K) {
  __shared__ bf16u sA[4][256 * 32];   // 4 x 16 KB
  __shared__ bf16u sB[4][128 * 32];   // 4 x 8 KB   (96 KB total)
  const int z = blockIdx.z;
  const bf16u* __restrict__ A = p.A[z];
  const bf16u* __restrict__ W = p.W[z];
  const float* __restrict__ bias = p.bias[z];

  const int tid  = threadIdx.x;
  const int wave = tid >> 6;          // 0..7
  const int lane = tid & 63;
  const int bn = blockIdx.x, bm = blockIdx.y;

  const int rg0 = wave * 8 + (lane >> 3);   // 0..63
  const int sp  = (lane & 7) ^ (rg0 & 7);
  const int srow = rg0 * 2 + (sp >> 2);     // 0..127
  const int sch  = sp & 3;
  const bf16u* agA = A + (size_t)(bm * 256 + srow) * K + sch * 8;
  const bf16u* wgB = W + (size_t)(bn * 128 + srow) * K + sch * 8;
  const int ldsoff = wave * 512;            // (wave*8 rgrps) * 64 elems

  const int wm = wave >> 1, wn = wave & 1;  // 4M x 2N waves, wave tile 64x64
  const int q = lane >> 4, cl = lane & 15;

  int aoff[4], boff[4];
#pragma unroll
  for (int m = 0; m < 4; ++m) {
    int row = wm * 64 + m * 16 + cl;
    aoff[m] = (row >> 1) * 64 + (((((row & 1) << 2) | q) ^ ((row >> 1) & 7)) * 8);
  }
#pragma unroll
  for (int j = 0; j < 4; ++j) {
    int row = wn * 64 + j * 16 + cl;
    boff[j] = (row >> 1) * 64 + (((((row & 1) << 2) | q) ^ ((row >> 1) & 7)) * 8);
  }

  f32x4 acc[4][4] = {};
  const int NT = K >> 5;   // 32-wide K-tiles (gates: 32; requires NT >= 4)

#define STG_A(buf, t)                                                         \
  do {                                                                        \
    __builtin_amdgcn_global_load_lds((const AS1 void*)(agA + (t) * 32),       \
        (AS3 void*)&sA[buf][ldsoff], 16, 0, 0);                               \
    __builtin_amdgcn_global_load_lds((const AS1 void*)(agA + (t) * 32 + (size_t)128 * K), \
        (AS3 void*)&sA[buf][ldsoff + 4096], 16, 0, 0);                        \
  } while (0)
#define STG_B(buf, t)                                                         \
  do {                                                                        \
    __builtin_amdgcn_global_load_lds((const AS1 void*)(wgB + (t) * 32),       \
        (AS3 void*)&sB[buf][ldsoff], 16, 0, 0);                               \
  } while (0)

  // prologue: stage tiles 0,1,2 (9 loads/thread in flight)
  STG_A(0, 0); STG_B(0, 0);
  STG_A(1, 1); STG_B(1, 1);
  STG_A(2, 2); STG_B(2, 2);
  asm volatile("s_waitcnt vmcnt(6)" ::: "memory");   // tile 0 landed
  __builtin_amdgcn_s_barrier();
  asm volatile("" ::: "memory");

  for (int t = 0; t < NT; ++t) {
    const int cb = t & 3;
    const int pb = (t + 3) & 3;
    const bool st = (t + 3) < NT;
    bf16x8 af[4], b0, b1;
    // ---------------- phase 1: A frags + B j0,j1 ----------------
#pragma unroll
    for (int m = 0; m < 4; ++m) af[m] = *(const bf16x8*)&sA[cb][aoff[m]];
    b0 = *(const bf16x8*)&sB[cb][boff[0]];
    b1 = *(const bf16x8*)&sB[cb][boff[1]];
    if (st) STG_A(pb, t + 3);
    __builtin_amdgcn_s_barrier();
    asm volatile("" ::: "memory");
    __builtin_amdgcn_s_setprio(1);
#pragma unroll
    for (int m = 0; m < 4; ++m) {
      acc[m][0] = __builtin_amdgcn_mfma_f32_16x16x32_bf16(af[m], b0, acc[m][0], 0, 0, 0);
      acc[m][1] = __builtin_amdgcn_mfma_f32_16x16x32_bf16(af[m], b1, acc[m][1], 0, 0, 0);
    }
    __builtin_amdgcn_s_setprio(0);
    __builtin_amdgcn_s_barrier();
    asm volatile("" ::: "memory");
    // ---------------- phase 2: B j2,j3 ----------------
    b0 = *(const bf16x8*)&sB[cb][boff[2]];
    b1 = *(const bf16x8*)&sB[cb][boff[3]];
    if (st) STG_B(pb, t + 3);
    {
      int nif = NT - 1 - t; if (nif > 3) nif = 3;
      if (nif >= 3)      asm volatile("s_waitcnt vmcnt(6)" ::: "memory");
      else if (nif == 2) asm volatile("s_waitcnt vmcnt(3)" ::: "memory");
      else if (nif == 1) asm volatile("s_waitcnt vmcnt(0)" ::: "memory");
    }
    __builtin_amdgcn_s_barrier();
    asm volatile("" ::: "memory");
    __builtin_amdgcn_s_setprio(1);
#pragma unroll
    for (int m = 0; m < 4; ++m) {
      acc[m][2] = __builtin_amdgcn_mfma_f32_16x16x32_bf16(af[m], b0, acc[m][2], 0, 0, 0);
      acc[m][3] = __builtin_amdgcn_mfma_f32_16x16x32_bf16(af[m], b1, acc[m][3], 0, 0, 0);
    }
    __builtin_amdgcn_s_setprio(0);
    __builtin_amdgcn_s_barrier();
    asm volatile("" ::: "memory");
  }
#undef STG_A
#undef STG_B

  float bv[4];
#pragma unroll
  for (int j = 0; j < 4; ++j)
    bv[j] = bias[bn * 128 + wn * 64 + j * 16 + cl];

  const int row0 = bm * 256 + wm * 64 + q * 4;
  const int col0 = bn * 128 + wn * 64 + cl;
#pragma unroll
  for (int m = 0; m < 4; ++m)
#pragma unroll
    for (int j = 0; j < 4; ++j)
#pragma unroll
      for (int r = 0; r < 4; ++r) {
        float v = acc[m][j][r] + bv[j];
        size_t off = (size_t)(row0 + m * 16 + r) * N + (col0 + j * 16);
        ((bf16u*)p.C[z])[off] = (bf16u)f2b(v);
      }
}

// Heads GEMM: A[M,1024] @ Wp[2304,1024]^T + biasp[2304], packed [mu|sg|pi].
// Tile 64x128 (proven round-0 config); head = bn/6 uniform per block.
// mu -> out, softplus(sg) -> out+HS, pi raw fp32 -> rawpi. Head col stride 768.
__global__ __launch_bounds__(256)
void gemm_heads(const bf16u* __restrict__ A, const bf16u* __restrict__ Wp,
                const float* __restrict__ biasp, float* __restrict__ out_mu,
                float* __restrict__ out_sg, float* __restrict__ rawpi,
                int outHS) {
  constexpr int K = 1024;
  __shared__ bf16u sA[64 * 64];
  __shared__ bf16u sB[128 * 64];
  const int tid  = threadIdx.x;
  const int wave = tid >> 6;
  const int lane = tid & 63;
  const int bn = blockIdx.x, bm = blockIdx.y;

  const int srA = wave * 16 + (lane >> 3);
  const int srB = wave * 32 + (lane >> 3);
  const int kc  = (lane & 7) ^ ((lane >> 3) & 7);
  const bf16u* ag = A + (size_t)(bm * 64 + srA) * K + kc * 8;
  const bf16u* wg = Wp + (size_t)(bn * 128 + srB) * K + kc * 8;

  const int wm = wave >> 1, wn = wave & 1;
  const int q = lane >> 4, cl = lane & 15;

  int aoff[2][2], boff[4][2];
#pragma unroll
  for (int i = 0; i < 2; ++i) {
    int m = wm * 32 + i * 16 + cl;
#pragma unroll
    for (int kk = 0; kk < 2; ++kk)
      aoff[i][kk] = m * 64 + (((q + kk * 4) ^ (m & 7)) * 8);
  }
#pragma unroll
  for (int j = 0; j < 4; ++j) {
    int n = wn * 64 + j * 16 + cl;
#pragma unroll
    for (int kk = 0; kk < 2; ++kk)
      boff[j][kk] = n * 64 + (((q + kk * 4) ^ (n & 7)) * 8);
  }

  f32x4 acc[2][4] = {};
  for (int k0 = 0; k0 < K; k0 += 64) {
#pragma unroll
    for (int t = 0; t < 2; ++t)
      __builtin_amdgcn_global_load_lds(
          (const AS1 void*)(ag + k0 + (size_t)t * 8 * K),
          (AS3 void*)&sA[wave * 1024 + t * 512],
          16, 0, 0);
#pragma unroll
    for (int t = 0; t < 4; ++t)
      __builtin_amdgcn_global_load_lds(
          (const AS1 void*)(wg + k0 + (size_t)t * 8 * K),
          (AS3 void*)&sB[wave * 2048 + t * 512],
          16, 0, 0);
    __syncthreads();
#pragma unroll
    for (int kk = 0; kk < 2; ++kk) {
      bf16x8 af[2], bfr[4];
#pragma unroll
      for (int i = 0; i < 2; ++i) af[i] = *(const bf16x8*)&sA[aoff[i][kk]];
#pragma unroll
      for (int j = 0; j < 4; ++j) bfr[j] = *(const bf16x8*)&sB[boff[j][kk]];
#pragma unroll
      for (int i = 0; i < 2; ++i)
#pragma unroll
        for (int j = 0; j < 4; ++j)
          acc[i][j] = __builtin_amdgcn_mfma_f32_16x16x32_bf16(af[i], bfr[j], acc[i][j], 0, 0, 0);
    }
    __syncthreads();
  }

  float bv[4];
#pragma unroll
  for (int j = 0; j < 4; ++j)
    bv[j] = biasp[bn * 128 + wn * 64 + j * 16 + cl];

  const int head = bn / 6;                       // 0:mu 1:sg 2:pi
  const int ch0 = (bn % 6) * 128 + wn * 64 + cl; // col within head
  const int row0 = bm * 64 + wm * 32 + q * 4;
#pragma unroll
  for (int i = 0; i < 2; ++i)
#pragma unroll
    for (int j = 0; j < 4; ++j)
#pragma unroll
      for (int r = 0; r < 4; ++r) {
        float v = acc[i][j][r] + bv[j];
        size_t off = (size_t)(row0 + i * 16 + r) * 768 + (ch0 + j * 16);
        if (head == 0) out_mu[off] = v;
        else if (head == 1)
          out_sg[off] = fmaxf(v, 0.f) + __logf(1.f + __expf(-fabsf(v)));
        else rawpi[off] = v;
      }
}

struct __align__(16) V8 { uint32_t u[4]; };
__device__ __forceinline__ float getf(const V8& v, int k) {
  uint32_t w = v.u[k >> 1];
  return b2f((bf16u)((k & 1) ? (w >> 16) : (w & 0xffffu)));
}
__device__ __forceinline__ void setb(V8& v, int k, float f) {
  uint32_t b = f2b(f) & 0xffffu;
  if (k & 1) v.u[k >> 1] = (v.u[k >> 1] & 0x0000ffffu) | (b << 16);
  else       v.u[k >> 1] = (v.u[k >> 1] & 0xffff0000u) | b;
}

// PyTorch GRU cell gate math (r,z,n order). 8 elems/thread.
template <int LAST>
__global__ __launch_bounds__(256)
void gru_gates(const bf16u* __restrict__ gi, const bf16u* __restrict__ gh,
               const float* __restrict__ hprev, float* __restrict__ hid_out,
               bf16u* __restrict__ nxt) {
  int t = blockIdx.x * 256 + threadIdx.x;
  size_t idx = (size_t)t * 8;
  int b = (int)(idx >> 10);
  int h = (int)(idx & 1023);
  size_t g0 = (size_t)b * 3072 + h;
  V8 ir  = *(const V8*)&gi[g0];
  V8 izv = *(const V8*)&gi[g0 + 1024];
  V8 inv = *(const V8*)&gi[g0 + 2048];
  V8 hr  = *(const V8*)&gh[g0];
  V8 hzv = *(const V8*)&gh[g0 + 1024];
  V8 hnv = *(const V8*)&gh[g0 + 2048];
  f4 hp0 = *(const f4*)&hprev[idx];
  f4 hp1 = *(const f4*)&hprev[idx + 4];
  f4 o0, o1;
  V8 no = {};
#pragma unroll
  for (int k = 0; k < 8; ++k) {
    float hpv = (k < 4) ? hp0[k] : hp1[k - 4];
    float r  = sigm(getf(ir, k) + getf(hr, k));
    float zg = sigm(getf(izv, k) + getf(hzv, k));
    float n  = ftanh(getf(inv, k) + r * getf(hnv, k));
    float hnew = (1.f - zg) * n + zg * hpv;
    if (k < 4) o0[k] = hnew; else o1[k - 4] = hnew;
    setb(no, k, LAST ? ftanh(hnew) : hnew);
  }
  *(f4*)&hid_out[idx] = o0;
  *(f4*)&hid_out[idx + 4] = o1;
  *(V8*)&nxt[idx] = no;
}

// softmax over g in {o, o+256, o+512} of rawpi [Bc][768] fp32 -> out fp32.
__global__ __launch_bounds__(256)
void pi_softmax(const float* __restrict__ rawpi, float* __restrict__ out) {
  int t = blockIdx.x * 256 + threadIdx.x;  // Bc*64 threads, 4 o's each
  int b = t >> 6;
  int o4 = (t & 63) << 2;
  size_t rb = (size_t)b * 768 + o4;
  f4 pi0 = *(const f4*)&rawpi[rb];
  f4 pi1 = *(const f4*)&rawpi[rb + 256];
  f4 pi2 = *(const f4*)&rawpi[rb + 512];
  f4 e0v, e1v, e2v;
#pragma unroll
  for (int c = 0; c < 4; ++c) {
    float m = fmaxf(fmaxf(pi0[c], pi1[c]), pi2[c]);
    float e0 = __expf(pi0[c] - m), e1 = __expf(pi1[c] - m), e2 = __expf(pi2[c] - m);
    float s = 1.f / (e0 + e1 + e2);
    e0v[c] = e0 * s; e1v[c] = e1 * s; e2v[c] = e2 * s;
  }
  *(f4*)&out[rb]       = e0v;
  *(f4*)&out[rb + 256] = e1v;
  *(f4*)&out[rb + 512] = e2v;
}

extern "C" void kernel_launch(void* const* d_in, const int* in_sizes, int n_in,
                              void* d_out, int out_size, void* d_ws, size_t ws_size,
                              hipStream_t stream) {
  const float* x      = (const float*)d_in[0];
  const float* hidden = (const float*)d_in[1];   // [2][4096][1024]
  const float* i2d_w  = (const float*)d_in[2];
  const float* i2d_b  = (const float*)d_in[3];
  const float* w_ih   = (const float*)d_in[4];   // [2][3072][1024]
  const float* w_hh   = (const float*)d_in[5];
  const float* b_ih   = (const float*)d_in[6];
  const float* b_hh   = (const float*)d_in[7];
  const float* mu_w   = (const float*)d_in[8];
  const float* mu_b   = (const float*)d_in[9];
  const float* sg_w   = (const float*)d_in[10];
  const float* sg_b   = (const float*)d_in[11];
  const float* pi_w   = (const float*)d_in[12];
  const float* pi_b   = (const float*)d_in[13];
  float* out = (float*)d_out;

  const size_t BH = 4194304;      // 4096*1024
  const int HS = 3145728;         // 4096*768
  float* hid_base = out + (size_t)3 * HS;

  dim3 blk(256, 1, 1);

  // ---- ws: bf16 weights (29.5 MB) + packed head bias fp32 ----
  bf16u* wb_i2d = (bf16u*)d_ws;             // 524288
  bf16u* wb_ih  = wb_i2d + 524288;          // 6291456 (both layers)
  bf16u* wb_hh  = wb_ih + 6291456;          // 6291456
  bf16u* wb_hd  = wb_hh + 6291456;          // 2359296 packed [mu|sg|pi][768][1024]
  float* biasp  = (float*)((char*)d_ws + 30932992);  // 2304 fp32
  const size_t wbytes = 30942208;

  { // one dispatch: 6 weight cvts + 3 bias copies
    CvtArgs a{};
    int nb = 0;
    auto seg = [&](const float* s, void* d, int count, int tobf) {
      a.s[a.nseg++] = {s, (char*)d, nb, count, tobf};
      nb += (count + 2047) / 2048;
    };
    seg(i2d_w, wb_i2d, 524288, 1);
    seg(w_ih,  wb_ih, 6291456, 1);
    seg(w_hh,  wb_hh, 6291456, 1);
    seg(mu_w,  wb_hd, 786432, 1);
    seg(sg_w,  wb_hd + 786432, 786432, 1);
    seg(pi_w,  wb_hd + 1572864, 786432, 1);
    seg(mu_b,  biasp, 768, 0);
    seg(sg_b,  biasp + 768, 768, 0);
    seg(pi_b,  biasp + 1536, 768, 0);
    cvt_multi<<<dim3(nb), blk, 0, stream>>>(a);
  }

  // ---- per-chunk scratch: Bc*19456 B ----
  int Bc = 4096;
  while (wbytes + (size_t)Bc * 19456 > ws_size && Bc > 256) Bc >>= 1;
  const int nchunk = 4096 / Bc;

  char* cbase = (char*)d_ws + wbytes;
  bf16u* ws0 = (bf16u*)cbase;                          // h1/hnew/hout bf16
  bf16u* xb  = (bf16u*)(cbase + (size_t)Bc * 2048);
  bf16u* hb0 = (bf16u*)(cbase + (size_t)Bc * 3072);
  bf16u* hb1 = (bf16u*)(cbase + (size_t)Bc * 5120);
  bf16u* gi  = (bf16u*)(cbase + (size_t)Bc * 7168);
  bf16u* gh  = (bf16u*)(cbase + (size_t)Bc * 13312);
  float* rawpi = (float*)gi;  // Bc*3072B, overlays dead gi

  for (int c = 0; c < nchunk; ++c) {
    const size_t off = (size_t)c * Bc;
    const float* h0_c = hidden + off * 1024;
    const float* h1_c = hidden + BH + off * 1024;

    { // one dispatch: x, h0, h1 cvt
      CvtArgs a{};
      int nb = 0;
      auto seg = [&](const float* s, void* d, int count) {
        a.s[a.nseg++] = {s, (char*)d, nb, count, 1};
        nb += (count + 2047) / 2048;
      };
      seg(x + off * 512, xb, Bc * 512);
      seg(h0_c, hb0, Bc * 1024);
      seg(h1_c, hb1, Bc * 1024);
      cvt_multi<<<dim3(nb), blk, 0, stream>>>(a);
    }

    { // h1 = relu(x @ i2d_w^T + b)  M=Bc N=1024 K=512, 64x128 tiles
      GemmPtrs p{};
      p.A[0] = xb; p.W[0] = wb_i2d; p.bias[0] = i2d_b; p.C[0] = ws0;
      gemm_bt<2, 1, 0><<<dim3(8, Bc / 64, 1), blk, 0, stream>>>(p, 1024, 512);
    }
    { // layer 0 gates: 256x128 fine-phase pipeline, 768-block grid
      GemmPtrs p{};
      p.A[0] = ws0; p.W[0] = wb_ih; p.bias[0] = b_ih; p.C[0] = gi;
      p.A[1] = hb0; p.W[1] = wb_hh; p.bias[1] = b_hh; p.C[1] = gh;
      gemm_gatesf<<<dim3(24, Bc / 256, 2), dim3(512, 1, 1), 0, stream>>>(p, 3072, 1024);
    }
    gru_gates<0><<<dim3(Bc / 2), blk, 0, stream>>>(
        gi, gh, h0_c, hid_base + off * 1024, ws0);
    { // layer 1 gates
      GemmPtrs p{};
      p.A[0] = ws0; p.W[0] = wb_ih + 3145728; p.bias[0] = b_ih + 3072; p.C[0] = gi;
      p.A[1] = hb1; p.W[1] = wb_hh + 3145728; p.bias[1] = b_hh + 3072; p.C[1] = gh;
      gemm_gatesf<<<dim3(24, Bc / 256, 2), dim3(512, 1, 1), 0, stream>>>(p, 3072, 1024);
    }
    gru_gates<1><<<dim3(Bc / 2), blk, 0, stream>>>(
        gi, gh, h1_c, hid_base + BH + off * 1024, ws0);
    // heads: 64x128 tiles, packed N=2304; mu/softplus direct, pi to raw
    gemm_heads<<<dim3(18, Bc / 64, 1), blk, 0, stream>>>(
        ws0, wb_hd, biasp, out + off * 768, out + HS + off * 768, rawpi, HS);
    pi_softmax<<<dim3(Bc / 4), blk, 0, stream>>>(rawpi, out + 2 * (size_t)HS + off * 768);
  }
}

// Round 5
// 367.963 us; speedup vs baseline: 1.1853x; 1.0911x over previous
//
#include <hip/hip_runtime.h>
#include <stdint.h>

typedef unsigned short bf16u;
typedef float f32x4 __attribute__((ext_vector_type(4)));
typedef short bf16x8 __attribute__((ext_vector_type(8)));
typedef float f4 __attribute__((ext_vector_type(4)));

#define AS1 __attribute__((address_space(1)))
#define AS3 __attribute__((address_space(3)))

__device__ __forceinline__ float b2f(bf16u u) {
  union { uint32_t i; float f; } v; v.i = ((uint32_t)u) << 16; return v.f;
}
__device__ __forceinline__ uint32_t f2b(float f) {
  union { float f; uint32_t i; } v; v.f = f;
  uint32_t i = v.i;
  return (i + 0x7FFFu + ((i >> 16) & 1u)) >> 16; // RNE
}
__device__ __forceinline__ float sigm(float x) { return 1.f / (1.f + __expf(-x)); }
__device__ __forceinline__ float ftanh(float x) {
  float e = __expf(2.f * x);
  return 1.f - 2.f / (e + 1.f);
}

// ---------------- multi-segment fp32->bf16 / fp32 copy ----------------
struct CvtSeg { const float* src; char* dst; int blk0; int count; int tobf16; };
struct CvtArgs { CvtSeg s[12]; int nseg; };

__global__ __launch_bounds__(256)
void cvt_multi(CvtArgs a) {
  int b = blockIdx.x, seg = 0;
  while (seg + 1 < a.nseg && b >= a.s[seg + 1].blk0) ++seg;
  const CvtSeg& S = a.s[seg];
  size_t idx = ((size_t)(b - S.blk0) * 2048) + (size_t)threadIdx.x * 8;
  if ((long long)idx >= S.count) return;
  f4 x = *(const f4*)&S.src[idx];
  f4 y = *(const f4*)&S.src[idx + 4];
  if (S.tobf16) {
    uint4 o;
    o.x = (f2b(x[0]) & 0xffffu) | (f2b(x[1]) << 16);
    o.y = (f2b(x[2]) & 0xffffu) | (f2b(x[3]) << 16);
    o.z = (f2b(y[0]) & 0xffffu) | (f2b(y[1]) << 16);
    o.w = (f2b(y[2]) & 0xffffu) | (f2b(y[3]) << 16);
    *(uint4*)((bf16u*)S.dst + idx) = o;
  } else {
    *(f4*)((float*)S.dst + idx) = x;
    *(f4*)((float*)S.dst + idx + 4) = y;
  }
}

// ------------------------------ GEMM ------------------------------
// C[M,N] = act(A[M,K] @ W[N,K]^T + bias[N]).  Tile: (IT*32) x 128, 4 waves,
// wave tile (IT*16) x 64.  LDS XOR-swizzled per-row: slot c of row r holds
// global k-chunk c^(r&7); fragment reads use slot g^(m&7) -> conflict-free.
struct GemmPtrs {
  const bf16u* A[2];
  const bf16u* W[2];
  const float* bias[2];
  void* C[2];
};

template <int IT, int ACT, int OUTF32>
__global__ __launch_bounds__(256)
void gemm_bt(GemmPtrs p, int N, int K) {
  constexpr int BM = IT * 32;
  __shared__ bf16u sA[BM * 64];
  __shared__ bf16u sB[128 * 64];
  const int z = blockIdx.z;
  const bf16u* __restrict__ A = p.A[z];
  const bf16u* __restrict__ W = p.W[z];
  const float* __restrict__ bias = p.bias[z];

  const int tid  = threadIdx.x;
  const int wave = tid >> 6;
  const int lane = tid & 63;
  const int bn = blockIdx.x, bm = blockIdx.y;

  const int srA = wave * (IT * 8) + (lane >> 3);
  const int srB = wave * 32 + (lane >> 3);
  const int kc  = (lane & 7) ^ ((lane >> 3) & 7);
  const bf16u* ag = A + (size_t)(bm * BM + srA) * K + kc * 8;
  const bf16u* wg = W + (size_t)(bn * 128 + srB) * K + kc * 8;

  const int wm = wave >> 1, wn = wave & 1;
  const int q = lane >> 4, cl = lane & 15;

  int aoff[IT][2], boff[4][2];
#pragma unroll
  for (int i = 0; i < IT; ++i) {
    int m = wm * (IT * 16) + i * 16 + cl;
#pragma unroll
    for (int kk = 0; kk < 2; ++kk)
      aoff[i][kk] = m * 64 + (((q + kk * 4) ^ (m & 7)) * 8);
  }
#pragma unroll
  for (int j = 0; j < 4; ++j) {
    int n = wn * 64 + j * 16 + cl;
#pragma unroll
    for (int kk = 0; kk < 2; ++kk)
      boff[j][kk] = n * 64 + (((q + kk * 4) ^ (n & 7)) * 8);
  }

  f32x4 acc[IT][4] = {};

  for (int k0 = 0; k0 < K; k0 += 64) {
#pragma unroll
    for (int t = 0; t < IT; ++t)
      __builtin_amdgcn_global_load_lds(
          (const AS1 void*)(ag + k0 + (size_t)t * 8 * K),
          (AS3 void*)&sA[wave * IT * 512 + t * 512],
          16, 0, 0);
#pragma unroll
    for (int t = 0; t < 4; ++t)
      __builtin_amdgcn_global_load_lds(
          (const AS1 void*)(wg + k0 + (size_t)t * 8 * K),
          (AS3 void*)&sB[wave * 2048 + t * 512],
          16, 0, 0);
    __syncthreads();
#pragma unroll
    for (int kk = 0; kk < 2; ++kk) {
      bf16x8 af[IT], bfr[4];
#pragma unroll
      for (int i = 0; i < IT; ++i) af[i] = *(const bf16x8*)&sA[aoff[i][kk]];
#pragma unroll
      for (int j = 0; j < 4; ++j) bfr[j] = *(const bf16x8*)&sB[boff[j][kk]];
#pragma unroll
      for (int i = 0; i < IT; ++i)
#pragma unroll
        for (int j = 0; j < 4; ++j)
          acc[i][j] = __builtin_amdgcn_mfma_f32_16x16x32_bf16(af[i], bfr[j], acc[i][j], 0, 0, 0);
    }
    __syncthreads();
  }

  float bv[4];
#pragma unroll
  for (int j = 0; j < 4; ++j)
    bv[j] = bias[bn * 128 + wn * 64 + j * 16 + cl];

  const int row0 = bm * BM + wm * (IT * 16) + q * 4;
  const int col0 = bn * 128 + wn * 64 + cl;
#pragma unroll
  for (int i = 0; i < IT; ++i)
#pragma unroll
    for (int j = 0; j < 4; ++j)
#pragma unroll
      for (int r = 0; r < 4; ++r) {
        float v = acc[i][j][r] + bv[j];
        if (ACT == 1) v = fmaxf(v, 0.f);
        size_t off = (size_t)(row0 + i * 16 + r) * N + (col0 + j * 16);
        if (OUTF32) ((float*)p.C[z])[off] = v;
        else        ((bf16u*)p.C[z])[off] = (bf16u)f2b(v);
      }
}

// ---------------- fused gates GEMM + GRU cell ----------------
// Block: 128 rows x 64 h-cols, 8 waves (4Mx2N), wave tile 32x32.
// 6 accumulator tiles: p=0,1,2 -> inp@w_ih^T gates (r,z,n); p=3,4,5 ->
// hprevb@w_hh^T gates.  All six share the SAME MFMA C fragment positions,
// so GRU math is pure per-thread epilogue arithmetic.
// LDS (80KB, single-buffered, 2 blocks/CU): rows [0,128)=inp,
// [128,256)=hprevb, [256+p*64, +64)=W panel p (p<3: w_ih gate p rows
// p*1024+c0..+64; p>=3: w_hh gate p-3).  Row-XOR swizzle: 16B slot c of row
// r holds k-chunk c^(r&7) (as gemm_bt).  Staging: 10 loads/thread; load t
// covers exactly rows [t*64, t*64+64) -> region is compile-time per t.
// Epilogue: r=sigm(ir+hr), z=sigm(iz+hz), n=tanh(in+r*hn),
// hnew=(1-z)n+z*hprev_f32; writes hid_out f32 and nxt bf16 (tanh if LAST).
template <int LAST>
__global__ __launch_bounds__(512)
void gru_fused(const bf16u* __restrict__ inp, const bf16u* __restrict__ hpb,
               const bf16u* __restrict__ wih, const bf16u* __restrict__ whh,
               const float* __restrict__ bih, const float* __restrict__ bhh,
               const float* __restrict__ hpf, float* __restrict__ hid_out,
               bf16u* __restrict__ nxt) {
  constexpr int K = 1024;
  __shared__ bf16u s[640 * 64];      // 80 KB
  const int tid  = threadIdx.x;
  const int wave = tid >> 6;
  const int lane = tid & 63;
  const int bn = blockIdx.x, bm = blockIdx.y;   // bn: hcol block (16), bm: rows (Bc/128)
  const int c0 = bn * 64;

  // staging: rr = row-within-region, kc = swizzled k-chunk, dst linear.
  const int rr  = tid >> 3;                 // 0..63
  const int kc  = (tid & 7) ^ (rr & 7);
  const int dst0 = rr * 64 + (tid & 7) * 8; // elems; + t*4096 per region round
  const bf16u* gI = inp + (size_t)(bm * 128 + rr) * K + kc * 8;   // t=0 (+64*K: t=1)
  const bf16u* gH = hpb + (size_t)(bm * 128 + rr) * K + kc * 8;   // t=2 (+64*K: t=3)
  const bf16u* gW[6];
#pragma unroll
  for (int p = 0; p < 6; ++p) {
    const bf16u* base = (p < 3) ? wih : whh;
    gW[p] = base + (size_t)((p % 3) * 1024 + c0 + rr) * K + kc * 8;
  }

  const int wm = wave >> 1, wn = wave & 1;  // 4 row-waves x 2 col-waves
  const int q = lane >> 4, cl = lane & 15;

  int aoff[2][2], boff[2][2];
#pragma unroll
  for (int i = 0; i < 2; ++i) {
    int ai = wm * 32 + i * 16 + cl;         // 0..127
#pragma unroll
    for (int kk = 0; kk < 2; ++kk)
      aoff[i][kk] = ai * 64 + (((q + kk * 4) ^ (ai & 7)) * 8);
  }
#pragma unroll
  for (int j = 0; j < 2; ++j) {
    int br = wn * 32 + j * 16 + cl;         // 0..63 within panel
#pragma unroll
    for (int kk = 0; kk < 2; ++kk)
      boff[j][kk] = (256 + br) * 64 + (((q + kk * 4) ^ (br & 7)) * 8); // + p*4096
  }

  f32x4 acc[6][2][2] = {};

  for (int k0 = 0; k0 < K; k0 += 64) {
    __builtin_amdgcn_global_load_lds((const AS1 void*)(gI + k0),
        (AS3 void*)&s[dst0], 16, 0, 0);
    __builtin_amdgcn_global_load_lds((const AS1 void*)(gI + k0 + (size_t)64 * K),
        (AS3 void*)&s[dst0 + 4096], 16, 0, 0);
    __builtin_amdgcn_global_load_lds((const AS1 void*)(gH + k0),
        (AS3 void*)&s[dst0 + 8192], 16, 0, 0);
    __builtin_amdgcn_global_load_lds((const AS1 void*)(gH + k0 + (size_t)64 * K),
        (AS3 void*)&s[dst0 + 12288], 16, 0, 0);
#pragma unroll
    for (int p = 0; p < 6; ++p)
      __builtin_amdgcn_global_load_lds((const AS1 void*)(gW[p] + k0),
          (AS3 void*)&s[dst0 + (4 + p) * 4096], 16, 0, 0);
    __syncthreads();
#pragma unroll
    for (int kk = 0; kk < 2; ++kk) {
      bf16x8 aI[2], aH[2];
#pragma unroll
      for (int i = 0; i < 2; ++i) {
        aI[i] = *(const bf16x8*)&s[aoff[i][kk]];
        aH[i] = *(const bf16x8*)&s[aoff[i][kk] + 8192];
      }
#pragma unroll
      for (int p = 0; p < 6; ++p) {
        bf16x8 b0 = *(const bf16x8*)&s[boff[0][kk] + p * 4096];
        bf16x8 b1 = *(const bf16x8*)&s[boff[1][kk] + p * 4096];
        if (p < 3) {
          acc[p][0][0] = __builtin_amdgcn_mfma_f32_16x16x32_bf16(aI[0], b0, acc[p][0][0], 0, 0, 0);
          acc[p][0][1] = __builtin_amdgcn_mfma_f32_16x16x32_bf16(aI[0], b1, acc[p][0][1], 0, 0, 0);
          acc[p][1][0] = __builtin_amdgcn_mfma_f32_16x16x32_bf16(aI[1], b0, acc[p][1][0], 0, 0, 0);
          acc[p][1][1] = __builtin_amdgcn_mfma_f32_16x16x32_bf16(aI[1], b1, acc[p][1][1], 0, 0, 0);
        } else {
          acc[p][0][0] = __builtin_amdgcn_mfma_f32_16x16x32_bf16(aH[0], b0, acc[p][0][0], 0, 0, 0);
          acc[p][0][1] = __builtin_amdgcn_mfma_f32_16x16x32_bf16(aH[0], b1, acc[p][0][1], 0, 0, 0);
          acc[p][1][0] = __builtin_amdgcn_mfma_f32_16x16x32_bf16(aH[1], b0, acc[p][1][0], 0, 0, 0);
          acc[p][1][1] = __builtin_amdgcn_mfma_f32_16x16x32_bf16(aH[1], b1, acc[p][1][1], 0, 0, 0);
        }
      }
    }
    __syncthreads();
  }

  float bI[3][2], bH[3][2];
#pragma unroll
  for (int g = 0; g < 3; ++g)
#pragma unroll
    for (int j = 0; j < 2; ++j) {
      int col = c0 + wn * 32 + j * 16 + cl;
      bI[g][j] = bih[g * 1024 + col];
      bH[g][j] = bhh[g * 1024 + col];
    }

#pragma unroll
  for (int i = 0; i < 2; ++i)
#pragma unroll
    for (int j = 0; j < 2; ++j)
#pragma unroll
      for (int r_ = 0; r_ < 4; ++r_) {
        int row = bm * 128 + wm * 32 + i * 16 + q * 4 + r_;
        int col = c0 + wn * 32 + j * 16 + cl;
        size_t o = (size_t)row * 1024 + col;
        float vir = acc[0][i][j][r_] + bI[0][j];
        float viz = acc[1][i][j][r_] + bI[1][j];
        float vin = acc[2][i][j][r_] + bI[2][j];
        float vhr = acc[3][i][j][r_] + bH[0][j];
        float vhz = acc[4][i][j][r_] + bH[1][j];
        float vhn = acc[5][i][j][r_] + bH[2][j];
        float rg = sigm(vir + vhr);
        float zg = sigm(viz + vhz);
        float ng = ftanh(vin + rg * vhn);
        float hnew = (1.f - zg) * ng + zg * hpf[o];
        hid_out[o] = hnew;
        nxt[o] = (bf16u)f2b(LAST ? ftanh(hnew) : hnew);
      }
}

// Heads GEMM: A[M,1024] @ Wp[2304,1024]^T + biasp[2304], packed [mu|sg|pi].
// Tile 64x128 (proven round-0 config); head = bn/6 uniform per block.
// mu -> out, softplus(sg) -> out+HS, pi raw fp32 -> rawpi. Head col stride 768.
__global__ __launch_bounds__(256)
void gemm_heads(const bf16u* __restrict__ A, const bf16u* __restrict__ Wp,
                const float* __restrict__ biasp, float* __restrict__ out_mu,
                float* __restrict__ out_sg, float* __restrict__ rawpi,
                int outHS) {
  constexpr int K = 1024;
  __shared__ bf16u sA[64 * 64];
  __shared__ bf16u sB[128 * 64];
  const int tid  = threadIdx.x;
  const int wave = tid >> 6;
  const int lane = tid & 63;
  const int bn = blockIdx.x, bm = blockIdx.y;

  const int srA = wave * 16 + (lane >> 3);
  const int srB = wave * 32 + (lane >> 3);
  const int kc  = (lane & 7) ^ ((lane >> 3) & 7);
  const bf16u* ag = A + (size_t)(bm * 64 + srA) * K + kc * 8;
  const bf16u* wg = Wp + (size_t)(bn * 128 + srB) * K + kc * 8;

  const int wm = wave >> 1, wn = wave & 1;
  const int q = lane >> 4, cl = lane & 15;

  int aoff[2][2], boff[4][2];
#pragma unroll
  for (int i = 0; i < 2; ++i) {
    int m = wm * 32 + i * 16 + cl;
#pragma unroll
    for (int kk = 0; kk < 2; ++kk)
      aoff[i][kk] = m * 64 + (((q + kk * 4) ^ (m & 7)) * 8);
  }
#pragma unroll
  for (int j = 0; j < 4; ++j) {
    int n = wn * 64 + j * 16 + cl;
#pragma unroll
    for (int kk = 0; kk < 2; ++kk)
      boff[j][kk] = n * 64 + (((q + kk * 4) ^ (n & 7)) * 8);
  }

  f32x4 acc[2][4] = {};
  for (int k0 = 0; k0 < K; k0 += 64) {
#pragma unroll
    for (int t = 0; t < 2; ++t)
      __builtin_amdgcn_global_load_lds(
          (const AS1 void*)(ag + k0 + (size_t)t * 8 * K),
          (AS3 void*)&sA[wave * 1024 + t * 512],
          16, 0, 0);
#pragma unroll
    for (int t = 0; t < 4; ++t)
      __builtin_amdgcn_global_load_lds(
          (const AS1 void*)(wg + k0 + (size_t)t * 8 * K),
          (AS3 void*)&sB[wave * 2048 + t * 512],
          16, 0, 0);
    __syncthreads();
#pragma unroll
    for (int kk = 0; kk < 2; ++kk) {
      bf16x8 af[2], bfr[4];
#pragma unroll
      for (int i = 0; i < 2; ++i) af[i] = *(const bf16x8*)&sA[aoff[i][kk]];
#pragma unroll
      for (int j = 0; j < 4; ++j) bfr[j] = *(const bf16x8*)&sB[boff[j][kk]];
#pragma unroll
      for (int i = 0; i < 2; ++i)
#pragma unroll
        for (int j = 0; j < 4; ++j)
          acc[i][j] = __builtin_amdgcn_mfma_f32_16x16x32_bf16(af[i], bfr[j], acc[i][j], 0, 0, 0);
    }
    __syncthreads();
  }

  float bv[4];
#pragma unroll
  for (int j = 0; j < 4; ++j)
    bv[j] = biasp[bn * 128 + wn * 64 + j * 16 + cl];

  const int head = bn / 6;                       // 0:mu 1:sg 2:pi
  const int ch0 = (bn % 6) * 128 + wn * 64 + cl; // col within head
  const int row0 = bm * 64 + wm * 32 + q * 4;
#pragma unroll
  for (int i = 0; i < 2; ++i)
#pragma unroll
    for (int j = 0; j < 4; ++j)
#pragma unroll
      for (int r = 0; r < 4; ++r) {
        float v = acc[i][j][r] + bv[j];
        size_t off = (size_t)(row0 + i * 16 + r) * 768 + (ch0 + j * 16);
        if (head == 0) out_mu[off] = v;
        else if (head == 1)
          out_sg[off] = fmaxf(v, 0.f) + __logf(1.f + __expf(-fabsf(v)));
        else rawpi[off] = v;
      }
}

// softmax over g in {o, o+256, o+512} of rawpi [Bc][768] fp32 -> out fp32.
__global__ __launch_bounds__(256)
void pi_softmax(const float* __restrict__ rawpi, float* __restrict__ out) {
  int t = blockIdx.x * 256 + threadIdx.x;  // Bc*64 threads, 4 o's each
  int b = t >> 6;
  int o4 = (t & 63) << 2;
  size_t rb = (size_t)b * 768 + o4;
  f4 pi0 = *(const f4*)&rawpi[rb];
  f4 pi1 = *(const f4*)&rawpi[rb + 256];
  f4 pi2 = *(const f4*)&rawpi[rb + 512];
  f4 e0v, e1v, e2v;
#pragma unroll
  for (int c = 0; c < 4; ++c) {
    float m = fmaxf(fmaxf(pi0[c], pi1[c]), pi2[c]);
    float e0 = __expf(pi0[c] - m), e1 = __expf(pi1[c] - m), e2 = __expf(pi2[c] - m);
    float s = 1.f / (e0 + e1 + e2);
    e0v[c] = e0 * s; e1v[c] = e1 * s; e2v[c] = e2 * s;
  }
  *(f4*)&out[rb]       = e0v;
  *(f4*)&out[rb + 256] = e1v;
  *(f4*)&out[rb + 512] = e2v;
}

extern "C" void kernel_launch(void* const* d_in, const int* in_sizes, int n_in,
                              void* d_out, int out_size, void* d_ws, size_t ws_size,
                              hipStream_t stream) {
  const float* x      = (const float*)d_in[0];
  const float* hidden = (const float*)d_in[1];   // [2][4096][1024]
  const float* i2d_w  = (const float*)d_in[2];
  const float* i2d_b  = (const float*)d_in[3];
  const float* w_ih   = (const float*)d_in[4];   // [2][3072][1024]
  const float* w_hh   = (const float*)d_in[5];
  const float* b_ih   = (const float*)d_in[6];
  const float* b_hh   = (const float*)d_in[7];
  const float* mu_w   = (const float*)d_in[8];
  const float* mu_b   = (const float*)d_in[9];
  const float* sg_w   = (const float*)d_in[10];
  const float* sg_b   = (const float*)d_in[11];
  const float* pi_w   = (const float*)d_in[12];
  const float* pi_b   = (const float*)d_in[13];
  float* out = (float*)d_out;

  const size_t BH = 4194304;      // 4096*1024
  const int HS = 3145728;         // 4096*768
  float* hid_base = out + (size_t)3 * HS;

  dim3 blk(256, 1, 1);

  // ---- ws: bf16 weights (29.5 MB) + packed head bias fp32 ----
  bf16u* wb_i2d = (bf16u*)d_ws;             // 524288
  bf16u* wb_ih  = wb_i2d + 524288;          // 6291456 (both layers)
  bf16u* wb_hh  = wb_ih + 6291456;          // 6291456
  bf16u* wb_hd  = wb_hh + 6291456;          // 2359296 packed [mu|sg|pi][768][1024]
  float* biasp  = (float*)((char*)d_ws + 30932992);  // 2304 fp32
  const size_t wbytes = 30942208;

  { // one dispatch: 6 weight cvts + 3 bias copies
    CvtArgs a{};
    int nb = 0;
    auto seg = [&](const float* s, void* d, int count, int tobf) {
      a.s[a.nseg++] = {s, (char*)d, nb, count, tobf};
      nb += (count + 2047) / 2048;
    };
    seg(i2d_w, wb_i2d, 524288, 1);
    seg(w_ih,  wb_ih, 6291456, 1);
    seg(w_hh,  wb_hh, 6291456, 1);
    seg(mu_w,  wb_hd, 786432, 1);
    seg(sg_w,  wb_hd + 786432, 786432, 1);
    seg(pi_w,  wb_hd + 1572864, 786432, 1);
    seg(mu_b,  biasp, 768, 0);
    seg(sg_b,  biasp + 768, 768, 0);
    seg(pi_b,  biasp + 1536, 768, 0);
    cvt_multi<<<dim3(nb), blk, 0, stream>>>(a);
  }

  // ---- per-chunk scratch: Bc*12288 B ----
  int Bc = 4096;
  while (wbytes + (size_t)Bc * 12288 > ws_size && Bc > 256) Bc >>= 1;
  const int nchunk = 4096 / Bc;

  char* cbase = (char*)d_ws + wbytes;
  bf16u* ws0  = (bf16u*)cbase;                          // h1 / layer1 nxt bf16
  bf16u* xb   = (bf16u*)(cbase + (size_t)Bc * 2048);
  bf16u* hb0  = (bf16u*)(cbase + (size_t)Bc * 3072);
  bf16u* hb1  = (bf16u*)(cbase + (size_t)Bc * 5120);
  bf16u* nxt0 = (bf16u*)(cbase + (size_t)Bc * 7168);    // layer0 nxt bf16
  float* rawpi = (float*)(cbase + (size_t)Bc * 9216);   // Bc*3072 B

  for (int c = 0; c < nchunk; ++c) {
    const size_t off = (size_t)c * Bc;
    const float* h0_c = hidden + off * 1024;
    const float* h1_c = hidden + BH + off * 1024;

    { // one dispatch: x, h0, h1 cvt
      CvtArgs a{};
      int nb = 0;
      auto seg = [&](const float* s, void* d, int count) {
        a.s[a.nseg++] = {s, (char*)d, nb, count, 1};
        nb += (count + 2047) / 2048;
      };
      seg(x + off * 512, xb, Bc * 512);
      seg(h0_c, hb0, Bc * 1024);
      seg(h1_c, hb1, Bc * 1024);
      cvt_multi<<<dim3(nb), blk, 0, stream>>>(a);
    }

    { // h1 = relu(x @ i2d_w^T + b)  M=Bc N=1024 K=512, 64x128 tiles
      GemmPtrs p{};
      p.A[0] = xb; p.W[0] = wb_i2d; p.bias[0] = i2d_b; p.C[0] = ws0;
      gemm_bt<2, 1, 0><<<dim3(8, Bc / 64, 1), blk, 0, stream>>>(p, 1024, 512);
    }
    // layer 0: fused gates GEMM + GRU cell
    gru_fused<0><<<dim3(16, Bc / 128), dim3(512, 1, 1), 0, stream>>>(
        ws0, hb0, wb_ih, wb_hh, b_ih, b_hh, h0_c,
        hid_base + off * 1024, nxt0);
    // layer 1
    gru_fused<1><<<dim3(16, Bc / 128), dim3(512, 1, 1), 0, stream>>>(
        nxt0, hb1, wb_ih + 3145728, wb_hh + 3145728, b_ih + 3072, b_hh + 3072,
        h1_c, hid_base + BH + off * 1024, ws0);
    // heads: 64x128 tiles, packed N=2304; mu/softplus direct, pi to raw
    gemm_heads<<<dim3(18, Bc / 64, 1), blk, 0, stream>>>(
        ws0, wb_hd, biasp, out + off * 768, out + HS + off * 768, rawpi, HS);
    pi_softmax<<<dim3(Bc / 4), blk, 0, stream>>>(rawpi, out + 2 * (size_t)HS + off * 768);
  }
}